// Round 4
// baseline (377.883 us; speedup 1.0000x reference)
//
#include <hip/hip_runtime.h>
#include <hip/hip_bf16.h>

// TinyCondEpsNet: out = relu([y|x|te] @ W1^T + b1) @ W2^T + b2
// B=524288, X=128, TE=32, IN=161, H=64.
// K-permutation used everywhere: k 0..127 = x, 128..159 = te, 160 = y_t,
// 161 = const 1.0 (folds fc1_bias), 162..191 = 0 (pad to 6 K-steps of 32).

typedef __bf16 bf16x8 __attribute__((ext_vector_type(8)));
typedef float  f32x4  __attribute__((ext_vector_type(4)));

#define NROWS   524288
#define KSTEPS  6
#define NTILES  4
// d_ws layout: [0, 24576) W1 B-fragments (4*6*64*8 bf16); [24576, +64000) te table bf16[1000][32]

static __device__ inline unsigned short f2bf(float x) {
    union { float f; unsigned u; } v; v.f = x;
    unsigned r = v.u + 0x7FFFu + ((v.u >> 16) & 1u);   // round-to-nearest-even
    return (unsigned short)(r >> 16);
}

static __device__ inline bf16x8 cvt8(float4 a, float4 b) {
    uint4 r;
    r.x = (unsigned)f2bf(a.x) | ((unsigned)f2bf(a.y) << 16);
    r.y = (unsigned)f2bf(a.z) | ((unsigned)f2bf(a.w) << 16);
    r.z = (unsigned)f2bf(b.x) | ((unsigned)f2bf(b.y) << 16);
    r.w = (unsigned)f2bf(b.z) | ((unsigned)f2bf(b.w) << 16);
    return __builtin_bit_cast(bf16x8, r);
}

// ---- setup: sinusoidal table, bf16[1000][32]: [t][0..15]=sin(t*f_j), [t][16..31]=cos ----
__global__ void setup_te_table(unsigned short* __restrict__ tab) {
    int tid = blockIdx.x * blockDim.x + threadIdx.x;
    if (tid >= 16000) return;
    int t = tid >> 4;
    int j = tid & 15;
    float e    = (-9.2103403719761836f * (float)j) * 0.0625f;  // -ln(10000)*j/16
    float freq = expf(e);
    float a    = (float)t * freq;
    tab[t * 32 + j]      = f2bf(sinf(a));
    tab[t * 32 + 16 + j] = f2bf(cosf(a));
}

// ---- setup: W1 (+bias fold) into MFMA B-fragment layout ----
// frag f = n*6+s, lane l: B[k][col], col = 16n + (l&15), k = 32s + 8*(l>>4) + j
__global__ void setup_w_frags(const float* __restrict__ w1, const float* __restrict__ b1,
                              unsigned short* __restrict__ wf) {
    int tid = blockIdx.x * blockDim.x + threadIdx.x;   // 0..1535 (6 blocks * 256)
    int l  = tid & 63;
    int fs = tid >> 6;          // 0..23
    int n  = fs / 6;
    int s  = fs % 6;
    int col = 16 * n + (l & 15);
    int g   = l >> 4;
    unsigned short vals[8] __attribute__((aligned(16)));
    #pragma unroll
    for (int j = 0; j < 8; ++j) {
        int k = 32 * s + 8 * g + j;
        float v;
        if      (k < 160)  v = w1[col * 161 + k + 1]; // x cols 1..128, te cols 129..160
        else if (k == 160) v = w1[col * 161 + 0];     // y_t col 0
        else if (k == 161) v = b1[col];               // bias via const-1 input
        else               v = 0.0f;
        vals[j] = f2bf(v);
    }
    ((uint4*)wf)[tid] = *(const uint4*)vals;
}

// ---- main: one wave = 2 M-tiles of 16 rows; no LDS ----
__global__ __launch_bounds__(256) void mlp_kernel(
    const float* __restrict__ y_t, const int* __restrict__ t, const float* __restrict__ x,
    const float* __restrict__ w2, const float* __restrict__ b2p,
    const unsigned short* __restrict__ wfrag, const unsigned short* __restrict__ tetab,
    float* __restrict__ out)
{
    const int tid = threadIdx.x;
    const int l   = tid & 63;
    const int wv  = tid >> 6;
    const int r   = l & 15;    // A-frag row within M-tile / also N-col index for D
    const int g   = l >> 4;    // k-group
    const long long blockRow0 = (long long)blockIdx.x * 128;

    float w2f[4];
    #pragma unroll
    for (int n = 0; n < NTILES; ++n) w2f[n] = w2[16 * n + r];
    const float b2 = b2p[0];

    const bf16x8* __restrict__ wfv = (const bf16x8*)wfrag;

    #pragma unroll
    for (int mtI = 0; mtI < 2; ++mtI) {
        const int mt = wv * 2 + mtI;                       // 0..7
        const long long arow = blockRow0 + mt * 16 + r;    // this lane's batch row

        // ---- A fragments ----
        bf16x8 af[KSTEPS];
        const float4* __restrict__ xrow = (const float4*)(x + arow * 128);
        #pragma unroll
        for (int s = 0; s < 4; ++s) {                      // k = 0..127: x
            float4 a = xrow[8 * s + 2 * g];
            float4 b = xrow[8 * s + 2 * g + 1];
            af[s] = cvt8(a, b);
        }
        {                                                  // k = 128..159: te gather
            int tval = t[arow];
            tval = tval < 0 ? 0 : (tval > 999 ? 999 : tval);   // clamp: no OOB even on garbage
            af[4] = *(const bf16x8*)(tetab + tval * 32 + 8 * g);
        }
        {                                                  // k = 160..191: y_t, 1.0, zeros
            uint4 u = make_uint4(0u, 0u, 0u, 0u);
            if (g == 0) u.x = (unsigned)f2bf(y_t[arow]) | (0x3F80u << 16);
            af[5] = __builtin_bit_cast(bf16x8, u);
        }

        // ---- MFMA: h[16 rows][64 units] ----
        f32x4 acc[NTILES];
        #pragma unroll
        for (int n = 0; n < NTILES; ++n) acc[n] = (f32x4){0.f, 0.f, 0.f, 0.f};
        #pragma unroll
        for (int n = 0; n < NTILES; ++n)
            #pragma unroll
            for (int s = 0; s < KSTEPS; ++s)
                acc[n] = __builtin_amdgcn_mfma_f32_16x16x32_bf16(
                    af[s], wfv[(n * 6 + s) * 64 + l], acc[n], 0, 0, 0);

        // ---- epilogue: relu, dot with w2, reduce over 16 lanes, store ----
        // D layout: h[row = 4g+v][col = 16n + r] in acc[n][v]
        float4 p;
        float* pp = &p.x;
        #pragma unroll
        for (int v = 0; v < 4; ++v) {
            float pv = 0.f;
            #pragma unroll
            for (int n = 0; n < NTILES; ++n) pv += w2f[n] * fmaxf(acc[n][v], 0.f);
            pv += __shfl_xor(pv, 1);
            pv += __shfl_xor(pv, 2);
            pv += __shfl_xor(pv, 4);
            pv += __shfl_xor(pv, 8);
            pp[v] = pv + b2;
        }
        if (r == 0) {
            *(float4*)(out + blockRow0 + mt * 16 + g * 4) = p;
        }
    }
}

extern "C" void kernel_launch(void* const* d_in, const int* in_sizes, int n_in,
                              void* d_out, int out_size, void* d_ws, size_t ws_size,
                              hipStream_t stream) {
    const float* y_t = (const float*)d_in[0];
    const int*   t   = (const int*)  d_in[1];
    const float* x   = (const float*)d_in[2];
    const float* w1  = (const float*)d_in[3];
    const float* b1  = (const float*)d_in[4];
    const float* w2  = (const float*)d_in[5];
    const float* b2  = (const float*)d_in[6];

    unsigned short* wfrag = (unsigned short*)d_ws;
    unsigned short* tetab = wfrag + 12288;   // 24576 bytes in

    setup_w_frags <<<6,  256, 0, stream>>>(w1, b1, wfrag);
    setup_te_table<<<63, 256, 0, stream>>>(tetab);
    mlp_kernel<<<NROWS / 128, 256, 0, stream>>>(y_t, t, x, w2, b2, wfrag, tetab, (float*)d_out);
}